// Round 6
// baseline (3586.406 us; speedup 1.0000x reference)
//
#include <hip/hip_runtime.h>
#include <stdint.h>
#include <stddef.h>

#define T_LEN  512
#define BATCH  64
#define NTAG   13
#define CT     64
#define NCHUNK 8

__device__ __forceinline__ float sigm(float x) { return 1.0f / (1.0f + expf(-x)); }

// Shared-memory overlay: lstm role and xg role never coexist in one block.
union __align__(16) SharedU {
    struct {
        float w[32][260];      // 33.3 KB
        float h[16][260];      // 16.6 KB
        float red[7][32][20];  // 17.9 KB
        float gate[32][17];    //  2.2 KB
    } l;                       // 70.0 KB total
    struct {
        float Wl[16][132];
        float El[16][132];
        int   tok[128];
    } g;                       // 17.4 KB
};

// ---------------------------------------------------------------------------
// Standalone xg GEMM (prologue only: chunk 0, no WAR hazard).
//   xg_ws[d][j][gate(1024)][b(64)] = emb[x[b][t]] . w_ih_d[gate] + biases
// grid (8, 32, 2), block 256.
// ---------------------------------------------------------------------------
__global__ __launch_bounds__(256) void xg_gemm(
    const int* __restrict__ x, const float* __restrict__ emb,
    const float* __restrict__ w_ih_f, const float* __restrict__ w_ih_b,
    const float* __restrict__ b_ih_f, const float* __restrict__ b_hh_f,
    const float* __restrict__ b_ih_b, const float* __restrict__ b_hh_b,
    float* __restrict__ xg_ws, int chunk)
{
    const int tid = threadIdx.x;
    const int mt = blockIdx.x;
    const int nt = blockIdx.y;
    const int d  = blockIdx.z;
    const int tbase = (d == 0 ? chunk : (NCHUNK - 1 - chunk)) * CT;
    const float* W  = (d == 0) ? w_ih_f : w_ih_b;
    const float* bi = (d == 0) ? b_ih_f : b_ih_b;
    const float* bh = (d == 0) ? b_hh_f : b_hh_b;

    __shared__ __align__(16) float Wl[16][132];
    __shared__ __align__(16) float El[16][132];
    __shared__ int tok[128];

    if (tid < 128) {
        int col = nt * 128 + tid;
        tok[tid] = x[(col & 63) * T_LEN + tbase + (col >> 6)];
    }
    __syncthreads();

    const int r  = tid >> 1;
    const int c8 = (tid & 1) * 8;
    const int tm = tid >> 4;
    const int tn = tid & 15;

    float acc[8][8];
#pragma unroll
    for (int i = 0; i < 8; i++)
#pragma unroll
        for (int jz = 0; jz < 8; jz++) acc[i][jz] = 0.0f;

    const float* wrow = &W[(size_t)(mt * 128 + r) * 256];
    const float* erow = &emb[(size_t)tok[r] * 256];

    for (int kb = 0; kb < 256; kb += 16) {
        float4 w0 = *(const float4*)&wrow[kb + c8];
        float4 w1 = *(const float4*)&wrow[kb + c8 + 4];
        float4 e0 = *(const float4*)&erow[kb + c8];
        float4 e1 = *(const float4*)&erow[kb + c8 + 4];
        __syncthreads();
        Wl[c8+0][r] = w0.x; Wl[c8+1][r] = w0.y; Wl[c8+2][r] = w0.z; Wl[c8+3][r] = w0.w;
        Wl[c8+4][r] = w1.x; Wl[c8+5][r] = w1.y; Wl[c8+6][r] = w1.z; Wl[c8+7][r] = w1.w;
        El[c8+0][r] = e0.x; El[c8+1][r] = e0.y; El[c8+2][r] = e0.z; El[c8+3][r] = e0.w;
        El[c8+4][r] = e1.x; El[c8+5][r] = e1.y; El[c8+6][r] = e1.z; El[c8+7][r] = e1.w;
        __syncthreads();
#pragma unroll
        for (int kk = 0; kk < 16; kk++) {
            float a[8], b[8];
            *(float4*)&a[0] = *(const float4*)&Wl[kk][tm*8];
            *(float4*)&a[4] = *(const float4*)&Wl[kk][tm*8+4];
            *(float4*)&b[0] = *(const float4*)&El[kk][tn*8];
            *(float4*)&b[4] = *(const float4*)&El[kk][tn*8+4];
#pragma unroll
            for (int i = 0; i < 8; i++)
#pragma unroll
                for (int jz = 0; jz < 8; jz++)
                    acc[i][jz] += a[i] * b[jz];
        }
    }

    const int colbase = nt * 128 + tn * 8;
    const int j  = colbase >> 6;
    const int b0 = colbase & 63;
#pragma unroll
    for (int gi = 0; gi < 8; gi++) {
        int g = mt * 128 + tm * 8 + gi;
        float bias = bi[g] + bh[g];
        float* dst = &xg_ws[(((size_t)(d * CT + j) * 1024 + g) << 6) + b0];
        float4 v0 = make_float4(acc[gi][0]+bias, acc[gi][1]+bias, acc[gi][2]+bias, acc[gi][3]+bias);
        float4 v1 = make_float4(acc[gi][4]+bias, acc[gi][5]+bias, acc[gi][6]+bias, acc[gi][7]+bias);
        *(float4*)dst       = v0;
        *(float4*)(dst + 4) = v1;
    }
}

// ---------------------------------------------------------------------------
// Fused per-chunk kernel. grid 768 x 256:
//   blocks 0..255   : lstm for chunk c (R5-identical internals, prio 3)
//   blocks 256..767 : xg helpers for chunk c+1 (prio 0), writing the SAME
//     single xg buffer. WAR guard: compute tile into regs, then poll lstm
//     progress flags (relaxed sc1), then store. Fwd pair {2nt,2nt+1}
//     overwritable when all 128 fwd flags >= c*64+2nt+2; bwd when all bwd
//     flags >= c*64+64-2nt. Capacity: 70 KB LDS/block (union) -> 2 blocks/CU
//     -> all 768 resident -> no deadlock (xg waits only on lstm flags; lstm
//     blocks are dispatched first and sync only among themselves).
// Sync mechanism unchanged from R3/R5: relaxed sc1 atomics only, no
// acquire/release cache maintenance.
// ---------------------------------------------------------------------------
__global__ __launch_bounds__(256) void fused_chunk(
    const float* __restrict__ xg_ws_c, float* __restrict__ xg_ws_w,
    const float* __restrict__ w_hh_f, const float* __restrict__ w_hh_b,
    float* h_ex, float* c_state, float* h_all, int* flags,
    const int* __restrict__ x, const float* __restrict__ emb,
    const float* __restrict__ w_ih_f, const float* __restrict__ w_ih_b,
    const float* __restrict__ b_ih_f, const float* __restrict__ b_hh_f,
    const float* __restrict__ b_ih_b, const float* __restrict__ b_hh_b,
    int chunk)
{
    __shared__ SharedU smem;
    const int tid = threadIdx.x;
    const int bid = blockIdx.x;

    if (bid < 256) {
        // ================= LSTM role =================
        __builtin_amdgcn_s_setprio(3);
        const int dg    = bid & 7;
        const int slice = bid >> 3;
        const int dir = dg & 1;
        const int grp = dg >> 1;
        const int h_base = slice * 8;
        const int sbase  = grp * 16;

        const float* W = dir ? w_hh_b : w_hh_f;
        for (int idx = tid; idx < 2048; idx += 256) {
            int f  = idx << 2;
            int rr = f >> 8;
            int c4 = f & 255;
            int row = (rr >> 3) * 256 + h_base + (rr & 7);
            *(float4*)&smem.l.w[rr][c4] = *(const float4*)&W[(size_t)row * 256 + c4];
        }

        const int ih_g = tid & 7;
        const int s_g  = tid >> 3;       // 0..15 for tid<128
        float c_val = 0.0f;
        if (tid < 128)
            c_val = c_state[(size_t)(dir * 64 + sbase + s_g) * 256 + h_base + ih_g];

        {   // initial h fill from parity-0 buffer
            const float* base = &h_ex[((size_t)dg * 16) * 256];
#pragma unroll
            for (int i = 0; i < 8; i++) {
                int pos = tid + 256 * i;
                int fo  = pos << 1;
                unsigned long long u64 = __hip_atomic_load(
                    (const unsigned long long*)(base + fo), __ATOMIC_RELAXED, __HIP_MEMORY_SCOPE_AGENT);
                float2 v = __builtin_bit_cast(float2, u64);
                *(float2*)&smem.l.h[fo >> 8][fo & 255] = v;
            }
        }
        __syncthreads();

        const int kc   = tid >> 5;
        const int tile = tid & 31;
        const int gt = tile >> 2;
        const int st = tile & 3;
        const float* wr[4] = { &smem.l.w[gt][0], &smem.l.w[8+gt][0], &smem.l.w[16+gt][0], &smem.l.w[24+gt][0] };
        const float* hr[4] = { &smem.l.h[st][0], &smem.l.h[4+st][0], &smem.l.h[8+st][0],  &smem.l.h[12+st][0] };

        float hv_prev = 0.0f;
        size_t ha_prev = 0;

#pragma unroll 1
        for (int tl = 0; tl < CT; tl++) {
            const int jslot = dir ? (CT - 1 - tl) : tl;
            const int t = (dir ? (NCHUNK - 1 - chunk) : chunk) * CT + jslot;
            const int sc = chunk * CT + tl + 1;
            const int par = sc & 1;

            float xg0 = 0.f, xg1 = 0.f, xg2 = 0.f, xg3 = 0.f;
            if (tid < 128) {
                if (tl > 0) h_all[ha_prev] = hv_prev;
                const float* xp = &xg_ws_c[(((size_t)(dir * CT + jslot) * 1024) + h_base + ih_g) * 64 + sbase + s_g];
                xg0 = xp[0];
                xg1 = xp[1 * 256 * 64];
                xg2 = xp[2 * 256 * 64];
                xg3 = xp[3 * 256 * 64];
            }

            float acc[4][4];
#pragma unroll
            for (int gi = 0; gi < 4; gi++)
#pragma unroll
                for (int si = 0; si < 4; si++) acc[gi][si] = 0.0f;

            const int j0 = kc * 32;
#pragma unroll
            for (int m = 0; m < 8; m++) {
                const int jj = j0 + m * 4;
                float4 w4[4], h4[4];
#pragma unroll
                for (int i = 0; i < 4; i++) w4[i] = *(const float4*)(wr[i] + jj);
#pragma unroll
                for (int i = 0; i < 4; i++) h4[i] = *(const float4*)(hr[i] + jj);
#pragma unroll
                for (int gi = 0; gi < 4; gi++)
#pragma unroll
                    for (int si = 0; si < 4; si++)
                        acc[gi][si] += w4[gi].x*h4[si].x + w4[gi].y*h4[si].y
                                     + w4[gi].z*h4[si].z + w4[gi].w*h4[si].w;
            }

            if (kc >= 1) {
#pragma unroll
                for (int gi = 0; gi < 4; gi++)
                    *(float4*)&smem.l.red[kc-1][tile][gi*4] =
                        make_float4(acc[gi][0], acc[gi][1], acc[gi][2], acc[gi][3]);
            }
            __syncthreads();
            if (kc == 0) {
#pragma unroll
                for (int p = 0; p < 7; p++)
#pragma unroll
                    for (int gi = 0; gi < 4; gi++) {
                        float4 v = *(const float4*)&smem.l.red[p][tile][gi*4];
                        acc[gi][0] += v.x; acc[gi][1] += v.y; acc[gi][2] += v.z; acc[gi][3] += v.w;
                    }
#pragma unroll
                for (int gi = 0; gi < 4; gi++)
#pragma unroll
                    for (int si = 0; si < 4; si++)
                        smem.l.gate[8*gi + gt][4*si + st] = acc[gi][si];
            }
            __syncthreads();

            if (tid < 128) {
                float gI = smem.l.gate[     ih_g][s_g] + xg0;
                float gF = smem.l.gate[8  + ih_g][s_g] + xg1;
                float gG = smem.l.gate[16 + ih_g][s_g] + xg2;
                float gO = smem.l.gate[24 + ih_g][s_g] + xg3;
                c_val = sigm(gF) * c_val + sigm(gI) * tanhf(gG);
                float hv = sigm(gO) * tanhf(c_val);
                __hip_atomic_store(&h_ex[(((size_t)par * 8 + dg) * 16 + s_g) * 256 + h_base + ih_g],
                                   hv, __ATOMIC_RELAXED, __HIP_MEMORY_SCOPE_AGENT);
                hv_prev = hv;
                ha_prev = ((size_t)t * 64 + sbase + s_g) * 512 + dir * 256 + h_base + ih_g;
            }
            __syncthreads();   // vmcnt(0) drain -> h_ex committed at coherence point

            if (tid == 0)
                __hip_atomic_store(&flags[dg * 32 + slice], sc, __ATOMIC_RELAXED, __HIP_MEMORY_SCOPE_AGENT);

            if (tid < 64) {
                const int* fp = &flags[dg * 32 + (tid & 31)];
                int spins = 0;
                int v = __hip_atomic_load(fp, __ATOMIC_RELAXED, __HIP_MEMORY_SCOPE_AGENT);
                while (__ballot(v < sc) != 0ull) {
                    if (++spins > 8) __builtin_amdgcn_s_sleep(1);
                    v = __hip_atomic_load(fp, __ATOMIC_RELAXED, __HIP_MEMORY_SCOPE_AGENT);
                    if (spins > (1 << 20)) break;   // safety valve
                }
            }
            __syncthreads();

            {   // coalesced 8-byte coherent reload -> LDS
                const float* base = &h_ex[(((size_t)par * 8 + dg) * 16) * 256];
#pragma unroll
                for (int i = 0; i < 8; i++) {
                    int pos = tid + 256 * i;
                    int fo  = pos << 1;
                    unsigned long long u64 = __hip_atomic_load(
                        (const unsigned long long*)(base + fo), __ATOMIC_RELAXED, __HIP_MEMORY_SCOPE_AGENT);
                    float2 v = __builtin_bit_cast(float2, u64);
                    *(float2*)&smem.l.h[fo >> 8][fo & 255] = v;
                }
            }
            __syncthreads();
        }

        if (tid < 128) {
            h_all[ha_prev] = hv_prev;
            c_state[(size_t)(dir * 64 + sbase + s_g) * 256 + h_base + ih_g] = c_val;
        }
    } else {
        // ================= XG-helper role (chunk+1) =================
        if (chunk == NCHUNK - 1) return;
        const int v  = bid - 256;
        const int mt = v & 7;
        const int nt = (v >> 3) & 31;
        const int d  = v >> 8;
        const int cn = chunk + 1;
        const int tbase = (d == 0 ? cn : (NCHUNK - 1 - cn)) * CT;
        const float* W  = (d == 0) ? w_ih_f : w_ih_b;
        const float* bi = (d == 0) ? b_ih_f : b_ih_b;
        const float* bh = (d == 0) ? b_hh_f : b_hh_b;

        if (tid < 128) {
            int col = nt * 128 + tid;
            smem.g.tok[tid] = x[(col & 63) * T_LEN + tbase + (col >> 6)];
        }
        __syncthreads();

        const int r  = tid >> 1;
        const int c8 = (tid & 1) * 8;
        const int tm = tid >> 4;
        const int tn = tid & 15;

        float acc[8][8];
#pragma unroll
        for (int i = 0; i < 8; i++)
#pragma unroll
            for (int jz = 0; jz < 8; jz++) acc[i][jz] = 0.0f;

        const float* wrow = &W[(size_t)(mt * 128 + r) * 256];
        const float* erow = &emb[(size_t)smem.g.tok[r] * 256];

        for (int kb = 0; kb < 256; kb += 16) {
            float4 w0 = *(const float4*)&wrow[kb + c8];
            float4 w1 = *(const float4*)&wrow[kb + c8 + 4];
            float4 e0 = *(const float4*)&erow[kb + c8];
            float4 e1 = *(const float4*)&erow[kb + c8 + 4];
            __syncthreads();
            smem.g.Wl[c8+0][r] = w0.x; smem.g.Wl[c8+1][r] = w0.y; smem.g.Wl[c8+2][r] = w0.z; smem.g.Wl[c8+3][r] = w0.w;
            smem.g.Wl[c8+4][r] = w1.x; smem.g.Wl[c8+5][r] = w1.y; smem.g.Wl[c8+6][r] = w1.z; smem.g.Wl[c8+7][r] = w1.w;
            smem.g.El[c8+0][r] = e0.x; smem.g.El[c8+1][r] = e0.y; smem.g.El[c8+2][r] = e0.z; smem.g.El[c8+3][r] = e0.w;
            smem.g.El[c8+4][r] = e1.x; smem.g.El[c8+5][r] = e1.y; smem.g.El[c8+6][r] = e1.z; smem.g.El[c8+7][r] = e1.w;
            __syncthreads();
#pragma unroll
            for (int kk = 0; kk < 16; kk++) {
                float a[8], b[8];
                *(float4*)&a[0] = *(const float4*)&smem.g.Wl[kk][tm*8];
                *(float4*)&a[4] = *(const float4*)&smem.g.Wl[kk][tm*8+4];
                *(float4*)&b[0] = *(const float4*)&smem.g.El[kk][tn*8];
                *(float4*)&b[4] = *(const float4*)&smem.g.El[kk][tn*8+4];
#pragma unroll
                for (int i = 0; i < 8; i++)
#pragma unroll
                    for (int jz = 0; jz < 8; jz++)
                        acc[i][jz] += a[i] * b[jz];
            }
        }

        // WAR guard: wait until every lstm block of direction d has consumed
        // slots {2nt, 2nt+1} of the CURRENT chunk from this buffer.
        {
            const int target = (d == 0) ? (chunk * CT + 2 * nt + 2)
                                        : (chunk * CT + CT - 2 * nt);
            if (tid < 64) {
                const int l = tid;
                const int* f0 = &flags[(d + 2 * (l >> 5)) * 32 + (l & 31)];
                const int* f1 = &flags[(d + 2 * ((l >> 5) + 2)) * 32 + (l & 31)];
                int spins = 0;
                for (;;) {
                    int a0 = __hip_atomic_load(f0, __ATOMIC_RELAXED, __HIP_MEMORY_SCOPE_AGENT);
                    int a1 = __hip_atomic_load(f1, __ATOMIC_RELAXED, __HIP_MEMORY_SCOPE_AGENT);
                    if (__ballot(a0 < target || a1 < target) == 0ull) break;
                    __builtin_amdgcn_s_sleep(8);
                    if (++spins > (1 << 20)) break;   // safety valve
                }
            }
            __syncthreads();
        }

        const int colbase = nt * 128 + tn * 8;
        const int j  = colbase >> 6;
        const int b0 = colbase & 63;
#pragma unroll
        for (int gi = 0; gi < 8; gi++) {
            int g = mt * 128 + tm * 8 + gi;
            float bias = bi[g] + bh[g];
            float* dst = &xg_ws_w[(((size_t)(d * CT + j) * 1024 + g) << 6) + b0];
            float4 v0 = make_float4(acc[gi][0]+bias, acc[gi][1]+bias, acc[gi][2]+bias, acc[gi][3]+bias);
            float4 v1 = make_float4(acc[gi][4]+bias, acc[gi][5]+bias, acc[gi][6]+bias, acc[gi][7]+bias);
            *(float4*)dst       = v0;
            *(float4*)(dst + 4) = v1;
        }
    }
}

// ---------------------------------------------------------------------------
__global__ __launch_bounds__(256) void emis_kernel(
    const float* __restrict__ h_all, const float* __restrict__ w_out,
    const float* __restrict__ b_out, float* __restrict__ emis)
{
    const int row = blockIdx.x * 16 + (threadIdx.x >> 4);
    const int k   = threadIdx.x & 15;
    const float* hr = &h_all[(size_t)row * 512];
    const float* wr = &w_out[(size_t)(k < NTAG ? k : 0) * 512];
    float acc = 0.0f;
#pragma unroll 8
    for (int e = 0; e < 512; e += 4) {
        float4 h4 = *(const float4*)&hr[e];
        float4 w4 = *(const float4*)&wr[e];
        acc += h4.x*w4.x + h4.y*w4.y + h4.z*w4.z + h4.w*w4.w;
    }
    if (k < NTAG) emis[(size_t)row * NTAG + k] = acc + b_out[k];
}

// ---------------------------------------------------------------------------
__global__ __launch_bounds__(64) void viterbi_kernel(
    const float* __restrict__ emis, const float* __restrict__ start_trans,
    const float* __restrict__ end_trans, const float* __restrict__ trans,
    float* __restrict__ out)
{
    const int b = blockIdx.x;
    const int k = threadIdx.x;
    __shared__ float em[T_LEN * NTAG];
    __shared__ unsigned char bp[T_LEN][16];

    for (int t = k; t < T_LEN; t += 64) {
        const float* src = &emis[((size_t)t * 64 + b) * NTAG];
#pragma unroll
        for (int kk = 0; kk < NTAG; kk++)
            em[t * NTAG + kk] = src[kk];
    }
    __syncthreads();

    float tc[NTAG];
#pragma unroll
    for (int kp = 0; kp < NTAG; kp++)
        tc[kp] = (k < NTAG) ? trans[kp * NTAG + k] : 0.0f;

    float score = (k < NTAG) ? (start_trans[k] + em[k]) : -3.0e38f;

    for (int t = 1; t < T_LEN; t++) {
        float best = -3.0e38f;
        int bi = 0;
#pragma unroll
        for (int kp = 0; kp < NTAG; kp++) {
            float v = __shfl(score, kp) + tc[kp];
            if (v > best) { best = v; bi = kp; }   // strict > => first max (jnp.argmax)
        }
        if (k < NTAG) {
            score = best + em[t * NTAG + k];
            bp[t][k] = (unsigned char)bi;
        }
    }
    if (k < NTAG) score += end_trans[k];
    else score = -3.0e38f;
    __syncthreads();

    float bs = -3.0e38f;
    int tag = 0;
#pragma unroll
    for (int kk = 0; kk < NTAG; kk++) {
        float v = __shfl(score, kk);
        if (v > bs) { bs = v; tag = kk; }
    }
    if (k == 0) {
        out[32768 + b] = bs;
        int tg = tag;
        out[b * T_LEN + (T_LEN - 1)] = (float)tg;
        for (int t = T_LEN - 1; t >= 1; t--) {
            tg = bp[t][tg];
            out[b * T_LEN + t - 1] = (float)tg;
        }
    }
}

// ---------------------------------------------------------------------------
extern "C" void kernel_launch(void* const* d_in, const int* in_sizes, int n_in,
                              void* d_out, int out_size, void* d_ws, size_t ws_size,
                              hipStream_t stream)
{
    (void)in_sizes; (void)n_in; (void)out_size; (void)ws_size;
    const int*   x    = (const int*)  d_in[0];
    const float* emb  = (const float*)d_in[1];
    const float* wihf = (const float*)d_in[2];
    const float* whhf = (const float*)d_in[3];
    const float* bihf = (const float*)d_in[4];
    const float* bhhf = (const float*)d_in[5];
    const float* wihb = (const float*)d_in[6];
    const float* whhb = (const float*)d_in[7];
    const float* bihb = (const float*)d_in[8];
    const float* bhhb = (const float*)d_in[9];
    const float* wout = (const float*)d_in[10];
    const float* bout = (const float*)d_in[11];
    const float* stt  = (const float*)d_in[12];
    const float* ent  = (const float*)d_in[13];
    const float* trn  = (const float*)d_in[14];
    float* out = (float*)d_out;

    char* ws = (char*)d_ws;
    size_t off = 0;
    float* xg_ws = (float*)(ws + off); off += (size_t)2 * CT * 1024 * 64 * 4;   // 33.55 MB
    float* h_all = (float*)(ws + off); off += (size_t)T_LEN * 64 * 512 * 4;     // 67.11 MB
    float* h_ex  = (float*)(ws + off); off += (size_t)2 * 8 * 16 * 256 * 4;     // 256 KB
    float* c_st  = (float*)(ws + off); off += (size_t)2 * 64 * 256 * 4;         // 128 KB
    float* emis  = (float*)(ws + off); off += (size_t)T_LEN * 64 * NTAG * 4;    // 1.70 MB
    int*   flags = (int*)  (ws + off); off += 8 * 32 * 4;

    hipMemsetAsync(h_ex,  0, (size_t)2 * 8 * 16 * 256 * 4, stream);
    hipMemsetAsync(c_st,  0, (size_t)2 * 64 * 256 * 4, stream);
    hipMemsetAsync(flags, 0, 8 * 32 * 4, stream);

    // prologue: xg for chunk 0
    xg_gemm<<<dim3(8, 32, 2), 256, 0, stream>>>(x, emb, wihf, wihb,
                                                bihf, bhhf, bihb, bhhb, xg_ws, 0);
    // fused: lstm chunk c + xg helpers for chunk c+1 (same single buffer,
    // WAR-guarded by lstm progress flags)
    for (int c = 0; c < NCHUNK; c++) {
        fused_chunk<<<768, 256, 0, stream>>>(xg_ws, xg_ws, whhf, whhb,
                                             h_ex, c_st, h_all, flags,
                                             x, emb, wihf, wihb,
                                             bihf, bhhf, bihb, bhhb, c);
    }
    emis_kernel<<<2048, 256, 0, stream>>>(h_all, wout, bout, emis);
    viterbi_kernel<<<64, 64, 0, stream>>>(emis, stt, ent, trn, out);
}